// Round 7
// baseline (344.854 us; speedup 1.0000x reference)
//
#include <hip/hip_runtime.h>
#include <hip/hip_bf16.h>
#include <cmath>
#include <cstdint>
#include <cstddef>

// Problem constants: B=4, C=256, H=W=256, DS=4 -> h=w=64, N=4096, Cq=16
typedef unsigned short u16;
typedef __attribute__((ext_vector_type(8))) __bf16 bf16x8;
typedef __attribute__((ext_vector_type(4))) float f32x4;
typedef __attribute__((ext_vector_type(8))) unsigned short us8;
typedef __attribute__((ext_vector_type(4))) unsigned short us4;

// Workspace layout (bytes)
static const size_t OFF_ODS   = 0;            // [B][C][4096] fp32 out_ds, 16 MB
static const size_t OFF_QT    = 16777216;     // [B][4096][16] fp32, 1 MB
static const size_t OFF_KT    = 17825792;     // [B][4096][16] fp32, 1 MB
static const size_t OFF_VT    = 18874368;     // [B][256][4096] bf16 (V transposed), 8 MB
static const size_t OFF_SPART = 27262976;     // [1024 blocks][32] fp32 partial col-sums, 128 KB
static const size_t OFF_MEAN  = 27394048;     // 1 float

__device__ __forceinline__ void gl2lds16(const void* gsrc, void* ldst) {
  __builtin_amdgcn_global_load_lds(
      (const __attribute__((address_space(1))) unsigned int*)gsrc,
      (__attribute__((address_space(3))) unsigned int*)ldst, 16, 0, 0);
}

__device__ __forceinline__ float hmax4(float4 v) {
  return fmaxf(fmaxf(v.x, v.y), fmaxf(v.z, v.w));
}

// ---------------- fused maxpool + q/k/v 1x1 convs + column sums ----------------
// 1024 blocks = b(4) x yo(64) x quarter(4); 256 threads; ~29 KB LDS -> 5 blocks/CU.
// Each block: 16 tokens (pooled row yo, cols qtr*16..+16). x read exactly once.
__global__ __launch_bounds__(256) void k_front(const float* __restrict__ x,
                                               const float* __restrict__ Wq, const float* __restrict__ bq,
                                               const float* __restrict__ Wk, const float* __restrict__ bk,
                                               const float* __restrict__ Wv, const float* __restrict__ bv,
                                               float* __restrict__ qT, float* __restrict__ kT,
                                               u16* __restrict__ vT, float* __restrict__ Spart) {
  __shared__ float xs[256][20];        // pooled strip, padded (20480 B)
  __shared__ float part2[4][16][33];   // per-wave q/k partials (8448 B)
  const int blk = blockIdx.x;
  const int b   = blk >> 8;
  const int yo  = (blk >> 2) & 63;
  const int qtr = blk & 3;
  const int n0  = yo * 64 + qtr * 16;
  const int tid = threadIdx.x;

  // ---- pool: thread -> (c = ci*64 + tid>>2, 4 tokens at jc*4) ----
  {
    const int jc = tid & 3;
    const int crow = tid >> 2;
    const float* base = x + (size_t)b * 16777216u + (size_t)(4 * yo) * 256u + qtr * 64 + jc * 16;
#pragma unroll
    for (int ci = 0; ci < 4; ++ci) {
      int c = ci * 64 + crow;
      const float* pc = base + (size_t)c * 65536u;
      float m0 = -1e30f, m1 = -1e30f, m2 = -1e30f, m3 = -1e30f;
#pragma unroll
      for (int r = 0; r < 4; ++r) {
        const float4* row = reinterpret_cast<const float4*>(pc + r * 256);
        m0 = fmaxf(m0, hmax4(row[0]));
        m1 = fmaxf(m1, hmax4(row[1]));
        m2 = fmaxf(m2, hmax4(row[2]));
        m3 = fmaxf(m3, hmax4(row[3]));
      }
      *reinterpret_cast<float4*>(&xs[c][jc * 4]) = make_float4(m0, m1, m2, m3);
    }
  }
  __syncthreads();

  // ---- q/k partials: thread = (cg = tid>>4, tok = tid&15), c-range cg*16..+16 ----
  {
    const int cg = tid >> 4, tok = tid & 15;
    float qac[16], kac[16];
#pragma unroll
    for (int o = 0; o < 16; ++o) { qac[o] = 0.f; kac[o] = 0.f; }
#pragma unroll
    for (int i4 = 0; i4 < 4; ++i4) {
      float xv0 = xs[cg * 16 + i4 * 4 + 0][tok];
      float xv1 = xs[cg * 16 + i4 * 4 + 1][tok];
      float xv2 = xs[cg * 16 + i4 * 4 + 2][tok];
      float xv3 = xs[cg * 16 + i4 * 4 + 3][tok];
#pragma unroll
      for (int o = 0; o < 16; ++o) {
        float4 q4 = *reinterpret_cast<const float4*>(&Wq[o * 256 + cg * 16 + i4 * 4]);
        float4 k4 = *reinterpret_cast<const float4*>(&Wk[o * 256 + cg * 16 + i4 * 4]);
        qac[o] = fmaf(q4.x, xv0, fmaf(q4.y, xv1, fmaf(q4.z, xv2, fmaf(q4.w, xv3, qac[o]))));
        kac[o] = fmaf(k4.x, xv0, fmaf(k4.y, xv1, fmaf(k4.z, xv2, fmaf(k4.w, xv3, kac[o]))));
      }
    }
    // in-wave reduce over the 4 cg values resident in this wave (lanes +-16, +-32)
#pragma unroll
    for (int o = 0; o < 16; ++o) {
      qac[o] += __shfl_xor(qac[o], 16); qac[o] += __shfl_xor(qac[o], 32);
      kac[o] += __shfl_xor(kac[o], 16); kac[o] += __shfl_xor(kac[o], 32);
    }
    const int w = tid >> 6, lane = tid & 63;
    if (lane < 16) {
#pragma unroll
      for (int o = 0; o < 16; ++o) {
        part2[w][lane][o]      = qac[o];
        part2[w][lane][16 + o] = kac[o];
      }
    }
  }
  __syncthreads();

  // ---- final q/k reduce (512 outputs over 256 threads) + Spart ----
#pragma unroll
  for (int j = 0; j < 2; ++j) {
    int idx = tid + j * 256;
    int tt = idx >> 5, o = idx & 31;
    float s = part2[0][tt][o] + part2[1][tt][o] + part2[2][tt][o] + part2[3][tt][o];
    if (o < 16) qT[((size_t)b * 4096u + n0 + tt) * 16u + o]        = s + bq[o];
    else        kT[((size_t)b * 4096u + n0 + tt) * 16u + (o - 16)] = s + bk[o - 16];
  }
  if (tid < 32) {
    float s = 0.f;
#pragma unroll
    for (int tt = 0; tt < 16; ++tt)
#pragma unroll
      for (int w = 0; w < 4; ++w) s += part2[w][tt][tid];
    Spart[(size_t)blk * 32u + tid] = s;
  }

  // ---- v conv: thread = out-channel tid, 16-token register tile ----
  {
    float acc[16];
#pragma unroll
    for (int i = 0; i < 16; ++i) acc[i] = 0.f;
    const float* wrow = Wv + (size_t)tid * 256u;
    for (int kk = 0; kk < 64; ++kk) {
      float4 wv = *reinterpret_cast<const float4*>(&wrow[kk * 4]);
#pragma unroll
      for (int u = 0; u < 4; ++u) {
        int k = kk * 4 + u;
        float ws = (u == 0) ? wv.x : (u == 1) ? wv.y : (u == 2) ? wv.z : wv.w;
        float4 x0 = *reinterpret_cast<const float4*>(&xs[k][0]);
        float4 x1 = *reinterpret_cast<const float4*>(&xs[k][4]);
        float4 x2 = *reinterpret_cast<const float4*>(&xs[k][8]);
        float4 x3 = *reinterpret_cast<const float4*>(&xs[k][12]);
        acc[0]  = fmaf(ws, x0.x, acc[0]);  acc[1]  = fmaf(ws, x0.y, acc[1]);
        acc[2]  = fmaf(ws, x0.z, acc[2]);  acc[3]  = fmaf(ws, x0.w, acc[3]);
        acc[4]  = fmaf(ws, x1.x, acc[4]);  acc[5]  = fmaf(ws, x1.y, acc[5]);
        acc[6]  = fmaf(ws, x1.z, acc[6]);  acc[7]  = fmaf(ws, x1.w, acc[7]);
        acc[8]  = fmaf(ws, x2.x, acc[8]);  acc[9]  = fmaf(ws, x2.y, acc[9]);
        acc[10] = fmaf(ws, x2.z, acc[10]); acc[11] = fmaf(ws, x2.w, acc[11]);
        acc[12] = fmaf(ws, x3.x, acc[12]); acc[13] = fmaf(ws, x3.y, acc[13]);
        acc[14] = fmaf(ws, x3.z, acc[14]); acc[15] = fmaf(ws, x3.w, acc[15]);
      }
    }
    float bb = bv[tid];
    u16* dst = vT + ((size_t)b * 256u + tid) * 4096u + n0;
    us8 o0, o1;
#pragma unroll
    for (int i = 0; i < 8; ++i) {
      o0[i] = __builtin_bit_cast(u16, __float2bfloat16(acc[i] + bb));
      o1[i] = __builtin_bit_cast(u16, __float2bfloat16(acc[8 + i] + bb));
    }
    *reinterpret_cast<us8*>(dst)     = o0;
    *reinterpret_cast<us8*>(dst + 8) = o1;
  }
}

// ---------------- scalar mean of att from block partial sums ----------------
__global__ __launch_bounds__(64) void k_mean(const float* __restrict__ Spart,
                                             const float* __restrict__ bq, const float* __restrict__ bk,
                                             float* __restrict__ meanp) {
  int t = threadIdx.x;        // (b,o): b = t>>4, o = t&15
  int b = t >> 4, o = t & 15;
  float sq = 4096.0f * bq[o], sk = 4096.0f * bk[o];
  for (int blk = 0; blk < 256; ++blk) {
    const float* p = Spart + ((size_t)(b * 256 + blk)) * 32u;
    sq += p[o];
    sk += p[16 + o];
  }
  float pr = sq * sk;
#pragma unroll
  for (int off = 32; off > 0; off >>= 1) pr += __shfl_down(pr, off);
  if (t == 0) *meanp = pr * (1.0f / 67108864.0f);   // / (B*N*N)
}

// ---------------- one-pass MFMA flash: split-bf16 QK^T + masked softmax + PV ----------------
// 256 blocks, XCD-bijective remap: batch = bits1-2 of blockIdx -> each XCD serves ONE batch
// (2 MB V + 256 KB K fit its 4 MB L2). 512 threads = 8 waves (2/SIMD).
__global__ __launch_bounds__(512) void k_flash(const float* __restrict__ qT,
                                               const float* __restrict__ kT,
                                               const u16* __restrict__ vT,
                                               const float* __restrict__ meanp,
                                               float* __restrict__ ods) {
  __shared__ u16 vbuf[2][16384];       // [buf][c row(256) x kv(64)] linear, source-swizzled (64 KB)
  __shared__ u16 kfh[2][4][64][8];     // B-frag [k_hi|k_hi], fragment-linear (8 KB)
  __shared__ u16 kfl[2][4][64][8];     // B-frag [k_lo|k_lo] (8 KB)
  __shared__ u16 pfr[8][2][64][8];     // per-wave P A-frags (16 KB)

  const int orig = blockIdx.x;
  const int b    = (orig >> 1) & 3;                        // bits1-2 -> XCD pair per batch
  const int row0 = (((orig & 1) << 5) | (orig >> 3)) * 64; // bijective q-tile remap
  const int tid  = threadIdx.x;
  const int w    = tid >> 6;
  const int lane = tid & 63;
  const int wq   = w & 3;
  const int wc   = w >> 2;
  const int g    = lane >> 4;          // 0..3
  const int c16  = lane & 15;

  const float mean = *meanp;

  // ---- Q A-frags (split bf16: A1=[q_hi|q_lo], A2=[q_hi|0]) ----
  float qv[16];
  {
    const float* qrow = qT + ((size_t)b*4096 + row0 + 16*wq + c16) * 16;
#pragma unroll
    for (int i = 0; i < 4; ++i) {
      float4 t4 = reinterpret_cast<const float4*>(qrow)[i];
      qv[4*i] = t4.x; qv[4*i+1] = t4.y; qv[4*i+2] = t4.z; qv[4*i+3] = t4.w;
    }
  }
  u16 qhi[16], qlo[16];
#pragma unroll
  for (int i = 0; i < 16; ++i) {
    __hip_bfloat16 h = __float2bfloat16(qv[i]);
    float fh = __bfloat162float(h);
    __hip_bfloat16 lo = __float2bfloat16(qv[i] - fh);
    qhi[i] = __builtin_bit_cast(u16, h);
    qlo[i] = __builtin_bit_cast(u16, lo);
  }
  us8 a1u, a2u;
  {
    const bool koff8  = (g & 1);
    const bool lo_src = (g >= 2);
#pragma unroll
    for (int i = 0; i < 8; ++i) {
      u16 hs = koff8 ? qhi[i+8] : qhi[i];
      u16 ls = koff8 ? qlo[i+8] : qlo[i];
      a1u[i] = lo_src ? ls : hs;
      a2u[i] = lo_src ? (u16)0 : hs;
    }
  }
  const bf16x8 A1 = __builtin_bit_cast(bf16x8, a1u);
  const bf16x8 A2 = __builtin_bit_cast(bf16x8, a2u);

  f32x4 O[8];
#pragma unroll
  for (int i = 0; i < 8; ++i) O[i] = (f32x4){0.f, 0.f, 0.f, 0.f};
  float Lr[4] = {0.f, 0.f, 0.f, 0.f};
  float M = 0.0f;

  // K staging params (threads 0..255 only)
  const int kv_s = tid >> 2, t4v = tid & 3;
  const int ks = kv_s >> 4, kld0 = (kv_s & 15) + 16*(t4v >> 1), ki0 = 4*(t4v & 1);

  // ---- prologue: stage tile 0 ----
  {
    const u16* vsrc = vT + (size_t)b*256*4096;
#pragma unroll
    for (int i = 0; i < 4; ++i) {
      int u = i*512 + tid;
      int row = u >> 3, slot = u & 7;
      int sb = (slot*16) ^ ((row & 7) << 4);
      gl2lds16((const char*)(vsrc + (size_t)row*4096) + sb, (char*)&vbuf[0][0] + u*16);
    }
    if (tid < 256) {
      float4 kvec = *reinterpret_cast<const float4*>(kT + ((size_t)b*4096 + kv_s)*16 + 4*t4v);
      float kf[4] = {kvec.x, kvec.y, kvec.z, kvec.w};
      us4 h4, l4;
#pragma unroll
      for (int di = 0; di < 4; ++di) {
        __hip_bfloat16 h = __float2bfloat16(kf[di]);
        float fh = __bfloat162float(h);
        __hip_bfloat16 lo = __float2bfloat16(kf[di] - fh);
        h4[di] = __builtin_bit_cast(u16, h);
        l4[di] = __builtin_bit_cast(u16, lo);
      }
      *reinterpret_cast<us4*>(&kfh[0][ks][kld0][ki0])    = h4;
      *reinterpret_cast<us4*>(&kfh[0][ks][kld0+32][ki0]) = h4;
      *reinterpret_cast<us4*>(&kfl[0][ks][kld0][ki0])    = l4;
      *reinterpret_cast<us4*>(&kfl[0][ks][kld0+32][ki0]) = l4;
    }
  }
  __syncthreads();

  // ---- main loop over 64 KV tiles of 64 ----
  for (int t = 0; t < 64; ++t) {
    const int cur = t & 1, nxt = cur ^ 1;
    const int kv0n = ((t + 1) & 63) * 64;

    // [D] issue next-tile staging (K -> regs, V -> LDS via DMA)
    float4 kvec;
    if (tid < 256)
      kvec = *reinterpret_cast<const float4*>(kT + ((size_t)b*4096 + kv0n + kv_s)*16 + 4*t4v);
    {
      const u16* vsrc = vT + (size_t)b*256*4096 + kv0n;
#pragma unroll
      for (int i = 0; i < 4; ++i) {
        int u = i*512 + tid;
        int row = u >> 3, slot = u & 7;
        int sb = (slot*16) ^ ((row & 7) << 4);
        gl2lds16((const char*)(vsrc + (size_t)row*4096) + sb, (char*)&vbuf[nxt][0] + u*16);
      }
    }

    // [A] scores: 4 kv-subtiles x 2 MFMA (split-bf16)
    f32x4 S[4];
#pragma unroll
    for (int s = 0; s < 4; ++s) {
      bf16x8 bh = __builtin_bit_cast(bf16x8, *reinterpret_cast<const us8*>(&kfh[cur][s][lane][0]));
      bf16x8 bl = __builtin_bit_cast(bf16x8, *reinterpret_cast<const us8*>(&kfl[cur][s][lane][0]));
      f32x4 acc = (f32x4){0.f, 0.f, 0.f, 0.f};
      acc = __builtin_amdgcn_mfma_f32_16x16x32_bf16(A1, bh, acc, 0, 0, 0);
      acc = __builtin_amdgcn_mfma_f32_16x16x32_bf16(A2, bl, acc, 0, 0, 0);
      S[s] = acc;
    }

    // [B] mask + deferred-max online softmax (wave-wide M, THR=8)
    float pmax = -1e30f;
#pragma unroll
    for (int s = 0; s < 4; ++s)
#pragma unroll
      for (int r = 0; r < 4; ++r) {
        float v = S[s][r];
        v = (v < mean) ? 0.f : v;
        S[s][r] = v;
        pmax = fmaxf(pmax, v);
      }
    if (!__all(pmax <= M + 8.0f)) {
      float mw = pmax;
#pragma unroll
      for (int off = 1; off < 64; off <<= 1) mw = fmaxf(mw, __shfl_xor(mw, off));
      float Mn = fmaxf(M, mw);
      float sc = __expf(M - Mn);
#pragma unroll
      for (int i = 0; i < 8; ++i) {
        O[i][0] *= sc; O[i][1] *= sc; O[i][2] *= sc; O[i][3] *= sc;
      }
#pragma unroll
      for (int r = 0; r < 4; ++r) Lr[r] *= sc;
      M = Mn;
    }
    u16 pb[4][4];
#pragma unroll
    for (int s = 0; s < 4; ++s)
#pragma unroll
      for (int r = 0; r < 4; ++r) {
        float p = __expf(S[s][r] - M);
        Lr[r] += p;
        pb[s][r] = __builtin_bit_cast(u16, __float2bfloat16(p));
      }

    // [C] write P into per-wave A-frag copy
    {
      const int ib = lane & 7;
      const int t1 = (lane >> 3) & 1;
#pragma unroll
      for (int s = 0; s < 4; ++s) {
        const int c2 = s >> 1;
        const int ldb = 16 * ((2*s + t1) & 3) + 4*g;
#pragma unroll
        for (int r = 0; r < 4; ++r) pfr[w][c2][ldb + r][ib] = pb[s][r];
      }
    }
    asm volatile("s_waitcnt lgkmcnt(0)" ::: "memory");
    __builtin_amdgcn_sched_barrier(0);

    // [G] PV: 2 k-chunks x 8 c-subtiles (this wave's c-half)
#pragma unroll
    for (int c2 = 0; c2 < 2; ++c2) {
      bf16x8 pa = __builtin_bit_cast(bf16x8, *reinterpret_cast<const us8*>(&pfr[w][c2][lane][0]));
#pragma unroll
      for (int ct = 0; ct < 8; ++ct) {
        int row = (wc*8 + ct)*16 + c16;
        int off = (c2*64 + g*16) ^ ((lane & 7) << 4);
        bf16x8 vb = __builtin_bit_cast(bf16x8,
            *reinterpret_cast<const us8*>((const char*)&vbuf[cur][0] + row*128 + off));
        O[ct] = __builtin_amdgcn_mfma_f32_16x16x32_bf16(pa, vb, O[ct], 0, 0, 0);
      }
    }

    // [H] convert + write K frags for next tile
    if (tid < 256) {
      float kf[4] = {kvec.x, kvec.y, kvec.z, kvec.w};
      us4 h4, l4;
#pragma unroll
      for (int di = 0; di < 4; ++di) {
        __hip_bfloat16 h = __float2bfloat16(kf[di]);
        float fh = __bfloat162float(h);
        __hip_bfloat16 lo = __float2bfloat16(kf[di] - fh);
        h4[di] = __builtin_bit_cast(u16, h);
        l4[di] = __builtin_bit_cast(u16, lo);
      }
      *reinterpret_cast<us4*>(&kfh[nxt][ks][kld0][ki0])    = h4;
      *reinterpret_cast<us4*>(&kfh[nxt][ks][kld0+32][ki0]) = h4;
      *reinterpret_cast<us4*>(&kfl[nxt][ks][kld0][ki0])    = l4;
      *reinterpret_cast<us4*>(&kfl[nxt][ks][kld0+32][ki0]) = l4;
    }

    __syncthreads();
  }

  // ---- epilogue: reduce L across the 16 kv-lanes, write O/L to ods [b][c][n] ----
#pragma unroll
  for (int r = 0; r < 4; ++r) {
    float v = Lr[r];
#pragma unroll
    for (int off = 1; off < 16; off <<= 1) v += __shfl_xor(v, off);
    Lr[r] = v;
  }
  float inv[4];
#pragma unroll
  for (int r = 0; r < 4; ++r) inv[r] = 1.0f / Lr[r];
#pragma unroll
  for (int ct = 0; ct < 8; ++ct) {
    int c = (wc*8 + ct)*16 + c16;
    float* dst = ods + ((size_t)b*256 + c) * 4096u + row0 + 16*wq + 4*g;
    float4 o4 = make_float4(O[ct][0]*inv[0], O[ct][1]*inv[1], O[ct][2]*inv[2], O[ct][3]*inv[3]);
    *reinterpret_cast<float4*>(dst) = o4;
  }
}

// ---------------- bilinear 4x upsample + residual, 4 px/thread ----------------
__global__ __launch_bounds__(256) void k_up(const float* __restrict__ ods, const float* __restrict__ x,
                                            float* __restrict__ out) {
  unsigned idx4 = blockIdx.x * 256u + threadIdx.x;   // < 16777216
  int a  = (int)(idx4 & 63u);          // horizontal cell = output j strip [4a,4a+4)
  int i  = (int)((idx4 >> 6) & 255u);  // output row
  size_t bc = idx4 >> 14;              // b*256 + c

  float py = (i + 0.5f) * 0.25f - 0.5f;
  float y0f = floorf(py);
  float wy = py - y0f;
  int y0 = (int)y0f, y1 = y0 + 1;
  y0 = max(y0, 0); y1 = min(y1, 63);

  int xm1 = max(a - 1, 0), xp1 = min(a + 1, 63);

  const float* r0 = ods + bc * 4096u + y0 * 64;
  const float* r1 = ods + bc * 4096u + y1 * 64;
  float wy1 = 1.f - wy;
  float vm1 = wy1 * r0[xm1] + wy * r1[xm1];
  float v0  = wy1 * r0[a]   + wy * r1[a];
  float vp1 = wy1 * r0[xp1] + wy * r1[xp1];

  float4 xv = *reinterpret_cast<const float4*>(x + (size_t)idx4 * 4u);
  float4 o4;
  o4.x = fmaf(0.375f, vm1, 0.625f * v0) + xv.x;
  o4.y = fmaf(0.125f, vm1, 0.875f * v0) + xv.y;
  o4.z = fmaf(0.875f, v0, 0.125f * vp1) + xv.z;
  o4.w = fmaf(0.625f, v0, 0.375f * vp1) + xv.w;
  *reinterpret_cast<float4*>(out + (size_t)idx4 * 4u) = o4;
}

extern "C" void kernel_launch(void* const* d_in, const int* in_sizes, int n_in,
                              void* d_out, int out_size, void* d_ws, size_t ws_size,
                              hipStream_t stream) {
  const float* x  = (const float*)d_in[0];
  const float* Wq = (const float*)d_in[1];
  const float* bq = (const float*)d_in[2];
  const float* Wk = (const float*)d_in[3];
  const float* bk = (const float*)d_in[4];
  const float* Wv = (const float*)d_in[5];
  const float* bv = (const float*)d_in[6];
  float* out = (float*)d_out;

  char* ws = (char*)d_ws;
  float* ods   = (float*)(ws + OFF_ODS);
  float* qT    = (float*)(ws + OFF_QT);
  float* kT    = (float*)(ws + OFF_KT);
  u16*   vT    = (u16*)(ws + OFF_VT);
  float* Spart = (float*)(ws + OFF_SPART);
  float* mnp   = (float*)(ws + OFF_MEAN);

  k_front<<<dim3(1024), dim3(256), 0, stream>>>(x, Wq, bq, Wk, bk, Wv, bv, qT, kT, vT, Spart);
  k_mean<<<dim3(1), dim3(64), 0, stream>>>(Spart, bq, bk, mnp);
  k_flash<<<dim3(256), dim3(512), 0, stream>>>(qT, kT, vT, mnp, ods);
  k_up<<<dim3(65536), dim3(256), 0, stream>>>(ods, x, out);
}